// Round 1
// baseline (1867.581 us; speedup 1.0000x reference)
//
#include <hip/hip_runtime.h>
#include <hip/hip_bf16.h>
#include <stdint.h>

#define K_IN 49152
#define EMB  2048
#define NQ   2048
#define NS   1024
#define NW   64
#define MA   2176   // 17*128 padded rows: [0,2048)=query, [2048,2112)=protos, rest garbage
#define MV   2112

typedef __bf16 bf16x8 __attribute__((ext_vector_type(8)));
typedef float  f32x4  __attribute__((ext_vector_type(4)));

__device__ __forceinline__ unsigned short f2bf(float f) {
  union { float f; uint32_t u; } v; v.f = f;
  uint32_t u = v.u;
  return (unsigned short)((u + 0x7FFFu + ((u >> 16) & 1u)) >> 16);  // RNE
}

#define GLDS16(g, l) __builtin_amdgcn_global_load_lds( \
    (__attribute__((address_space(1))) void*)(g),      \
    (__attribute__((address_space(3))) void*)(l), 16, 0, 0)

// ---------- K1: per-class row index lists ----------
__global__ void k_build_index(const int* __restrict__ labels, int* __restrict__ rowsIdx,
                              int* __restrict__ counts) {
  int t = threadIdx.x;
  if (t < NW) counts[t] = 0;
  __syncthreads();
  if (t < NS) {
    int lab = labels[t];
    int pos = atomicAdd(&counts[lab], 1);
    if (pos < 16) rowsIdx[lab * 16 + pos] = t;
  }
}

// ---------- K2: class-mean images -> bf16 rows [2048, 2112) of A ----------
__global__ void k_proto_mean(const float* __restrict__ sup, const int* __restrict__ rowsIdx,
                             const int* __restrict__ counts, unsigned short* __restrict__ Abf) {
  int c = blockIdx.y;
  int d0 = blockIdx.x * 1024 + threadIdx.x * 4;
  float4 s = make_float4(0.f, 0.f, 0.f, 0.f);
  int cnt = counts[c]; if (cnt > 16) cnt = 16;
  for (int j = 0; j < cnt; ++j) {
    int r = rowsIdx[c * 16 + j];
    float4 v = *(const float4*)(sup + (size_t)r * K_IN + d0);
    s.x += v.x; s.y += v.y; s.z += v.z; s.w += v.w;
  }
  float inv = 1.0f / (float)cnt;
  ushort4 o;
  o.x = f2bf(s.x * inv); o.y = f2bf(s.y * inv);
  o.z = f2bf(s.z * inv); o.w = f2bf(s.w * inv);
  *(ushort4*)(Abf + (size_t)(NQ + c) * K_IN + d0) = o;
}

// ---------- K3: query fp32 -> bf16 rows [0, 2048) of A ----------
__global__ void k_convert_q(const float* __restrict__ q, unsigned short* __restrict__ Abf) {
  size_t i4 = (size_t)blockIdx.x * blockDim.x + threadIdx.x;
  float4 v = *((const float4*)q + i4);
  ushort4 o; o.x = f2bf(v.x); o.y = f2bf(v.y); o.z = f2bf(v.z); o.w = f2bf(v.w);
  *((ushort4*)Abf + i4) = o;
}

// ---------- K4: W [K,E] fp32 -> Wt [E,K] bf16 (LDS-tiled transpose) ----------
__global__ void k_transpose_w(const float* __restrict__ W, unsigned short* __restrict__ Wt) {
  __shared__ float tile[64][65];
  int t = threadIdx.x;
  int k0 = blockIdx.x * 64, n0 = blockIdx.y * 64;
  int nl = t & 63, kb = (t >> 6) * 16;
  for (int r = 0; r < 16; ++r)
    tile[kb + r][nl] = W[(size_t)(k0 + kb + r) * EMB + n0 + nl];
  __syncthreads();
  int k2 = (t & 31) * 2, nb = (t >> 5) * 8;
  for (int r = 0; r < 8; ++r) {
    int n = nb + r;
    uint32_t lo = f2bf(tile[k2][n]);
    uint32_t hi = f2bf(tile[k2 + 1][n]);
    *(uint32_t*)(Wt + (size_t)(n0 + n) * K_IN + k0 + k2) = lo | (hi << 16);
  }
}

// ---------- K5: zero Z ----------
__global__ void k_zero(float* __restrict__ Z, int n4) {
  int i = blockIdx.x * blockDim.x + threadIdx.x;
  if (i < n4) ((float4*)Z)[i] = make_float4(0.f, 0.f, 0.f, 0.f);
}

// ---------- K6: bf16 MFMA GEMM, 128x128 tile, BK=32, split-K=3 ----------
__global__ __launch_bounds__(256, 3) void k_gemm(
    const unsigned short* __restrict__ Abf, const unsigned short* __restrict__ Wt,
    const float* __restrict__ bias, float* __restrict__ Z) {
  __shared__ unsigned short As[128 * 32];
  __shared__ unsigned short Bs[128 * 32];
  int tid = threadIdx.x;
  int rowBase = blockIdx.y * 128;
  int colBase = blockIdx.x * 128;
  int kbase   = blockIdx.z * (K_IN / 3);

  int r0 = tid >> 2;
  int kg = (tid & 3) * 8;
  const unsigned short* gA0 = Abf + (size_t)(rowBase + r0) * K_IN + kbase + kg;
  const unsigned short* gA1 = gA0 + (size_t)64 * K_IN;
  const unsigned short* gB0 = Wt  + (size_t)(colBase + r0) * K_IN + kbase + kg;
  const unsigned short* gB1 = gB0 + (size_t)64 * K_IN;
  unsigned short* lA0 = &As[r0 * 32 + kg];
  unsigned short* lA1 = &As[(64 + r0) * 32 + kg];
  unsigned short* lB0 = &Bs[r0 * 32 + kg];
  unsigned short* lB1 = &Bs[(64 + r0) * 32 + kg];

  int lane = tid & 63, wid = tid >> 6;
  int wm = wid >> 1, wn = wid & 1;
  int lrow = lane & 15, kgrp = (lane >> 4) * 8;
  const unsigned short* fa = &As[(wm * 64 + lrow) * 32 + kgrp];
  const unsigned short* fb = &Bs[(wn * 64 + lrow) * 32 + kgrp];

  f32x4 acc[4][4] = {};

  for (int kt = 0; kt < (K_IN / 3) / 32; ++kt) {
    int ko = kt * 32;
    GLDS16(gA0 + ko, lA0);
    GLDS16(gA1 + ko, lA1);
    GLDS16(gB0 + ko, lB0);
    GLDS16(gB1 + ko, lB1);
    __syncthreads();
    bf16x8 a[4], bb[4];
#pragma unroll
    for (int i = 0; i < 4; ++i) {
      a[i]  = *(const bf16x8*)(fa + i * 16 * 32);
      bb[i] = *(const bf16x8*)(fb + i * 16 * 32);
    }
#pragma unroll
    for (int i = 0; i < 4; ++i)
#pragma unroll
      for (int j = 0; j < 4; ++j)
        acc[i][j] = __builtin_amdgcn_mfma_f32_16x16x32_bf16(a[i], bb[j], acc[i][j], 0, 0, 0);
    __syncthreads();
  }

  int lquad = lane >> 4;
  bool addB = (blockIdx.z == 0);
#pragma unroll
  for (int i = 0; i < 4; ++i) {
#pragma unroll
    for (int j = 0; j < 4; ++j) {
      int m0 = rowBase + wm * 64 + i * 16 + lquad * 4;
      int n  = colBase + wn * 64 + j * 16 + lrow;
      float bv = addB ? bias[n] : 0.0f;
#pragma unroll
      for (int r = 0; r < 4; ++r)
        atomicAdd(&Z[(size_t)(m0 + r) * EMB + n], acc[i][j][r] + bv);
    }
  }
}

// ---------- K7: row norms of Z (rows [0, 2112)) ----------
__global__ void k_norms(const float* __restrict__ Z, float* __restrict__ norms) {
  int wid = threadIdx.x >> 6, lane = threadIdx.x & 63;
  int row = blockIdx.x * 4 + wid;
  const float4* Zr = (const float4*)(Z + (size_t)row * EMB);
  float s = 0.f;
  for (int i = lane; i < EMB / 4; i += 64) {
    float4 v = Zr[i];
    s += v.x * v.x + v.y * v.y + v.z * v.z + v.w * v.w;
  }
  for (int d = 32; d > 0; d >>= 1) s += __shfl_down(s, d, 64);
  if (lane == 0) norms[row] = sqrtf(s);
}

// ---------- K8: cosine scores ----------
__global__ void k_cosine(const float* __restrict__ Z, const float* __restrict__ norms,
                         float* __restrict__ out) {
  __shared__ float4 zq[4 * 512];
  int t = threadIdx.x;
  int q0 = blockIdx.x * 4;
  const float4* Z4 = (const float4*)Z;
  for (int v = 0; v < 8; ++v) {
    int idx = v * 256 + t;
    zq[idx] = Z4[(size_t)q0 * 512 + idx];
  }
  __syncthreads();
  int c = t & 63, qi = t >> 6;
  const float4* Zp = Z4 + (size_t)(NQ + c) * 512;
  const float4* Zq = &zq[qi * 512];
  float s = 0.f;
  for (int kv = 0; kv < 512; ++kv) {
    float4 p = Zp[kv];
    float4 q = Zq[kv];
    s += p.x * q.x + p.y * q.y + p.z * q.z + p.w * q.w;
  }
  float nq = norms[q0 + qi], np = norms[NQ + c];
  out[(size_t)(q0 + qi) * NW + c] = s / fmaxf(nq * np, 1e-6f);
}

extern "C" void kernel_launch(void* const* d_in, const int* in_sizes, int n_in,
                              void* d_out, int out_size, void* d_ws, size_t ws_size,
                              hipStream_t stream) {
  const float* sup    = (const float*)d_in[0];
  const int*   labels = (const int*)d_in[1];
  const float* qry    = (const float*)d_in[2];
  const float* W      = (const float*)d_in[3];
  const float* bias   = (const float*)d_in[4];
  float* out = (float*)d_out;

  char* w = (char*)d_ws;
  unsigned short* Abf = (unsigned short*)w;                       // 213,909,504 B
  unsigned short* Wt  = (unsigned short*)(w + 213909504u);        // 201,326,592 B
  float* Z     = (float*)(w + 415236096u);                        //  17,825,792 B
  float* norms = (float*)(w + 433061888u);                        //       8,448 B
  int* rowsIdx = (int*)(w + 433070336u);                          //       4,096 B
  int* counts  = (int*)(w + 433074432u);                          //         256 B

  k_build_index<<<1, 1024, 0, stream>>>(labels, rowsIdx, counts);
  k_proto_mean<<<dim3(48, 64), 256, 0, stream>>>(sup, rowsIdx, counts, Abf);
  k_convert_q<<<98304, 256, 0, stream>>>(qry, Abf);
  k_transpose_w<<<dim3(768, 32), 256, 0, stream>>>(W, Wt);
  k_zero<<<(MA * EMB / 4 + 255) / 256, 256, 0, stream>>>(Z, MA * EMB / 4);
  k_gemm<<<dim3(16, 17, 3), 256, 0, stream>>>(Abf, Wt, bias, Z);
  k_norms<<<528, 256, 0, stream>>>(Z, norms);
  k_cosine<<<512, 256, 0, stream>>>(Z, norms, out);
}

// Round 2
// 1526.276 us; speedup vs baseline: 1.2236x; 1.2236x over previous
//
#include <hip/hip_runtime.h>
#include <hip/hip_bf16.h>
#include <stdint.h>

#define K_IN 49152
#define EMB  2048
#define NQ   2048
#define NS   1024
#define NW   64
#define MA   2176   // 17*128 padded rows: [0,2048)=query, [2048,2112)=protos, rest garbage
#define MV   2112
#define EPS  1e-6f

typedef __bf16 bf16x8 __attribute__((ext_vector_type(8)));
typedef float  f32x4  __attribute__((ext_vector_type(4)));

__device__ __forceinline__ unsigned short f2bf(float f) {
  union { float f; uint32_t u; } v; v.f = f;
  uint32_t u = v.u;
  return (unsigned short)((u + 0x7FFFu + ((u >> 16) & 1u)) >> 16);  // RNE
}

#define GLDS16(g, l) __builtin_amdgcn_global_load_lds( \
    (__attribute__((address_space(1))) void*)(g),      \
    (__attribute__((address_space(3))) void*)(l), 16, 0, 0)

// ---------- K1: per-class row index lists ----------
__global__ void k_build_index(const int* __restrict__ labels, int* __restrict__ rowsIdx,
                              int* __restrict__ counts) {
  int t = threadIdx.x;
  if (t < NW) counts[t] = 0;
  __syncthreads();
  if (t < NS) {
    int lab = labels[t];
    int pos = atomicAdd(&counts[lab], 1);
    if (pos < 16) rowsIdx[lab * 16 + pos] = t;
  }
}

// ---------- K2: class-mean images -> bf16 rows [2048, 2112) of A ----------
__global__ void k_proto_mean(const float* __restrict__ sup, const int* __restrict__ rowsIdx,
                             const int* __restrict__ counts, unsigned short* __restrict__ Abf) {
  int c = blockIdx.y;
  int d0 = blockIdx.x * 1024 + threadIdx.x * 4;
  float4 s = make_float4(0.f, 0.f, 0.f, 0.f);
  int cnt = counts[c]; if (cnt > 16) cnt = 16;
  for (int j = 0; j < cnt; ++j) {
    int r = rowsIdx[c * 16 + j];
    float4 v = *(const float4*)(sup + (size_t)r * K_IN + d0);
    s.x += v.x; s.y += v.y; s.z += v.z; s.w += v.w;
  }
  float inv = 1.0f / (float)cnt;
  ushort4 o;
  o.x = f2bf(s.x * inv); o.y = f2bf(s.y * inv);
  o.z = f2bf(s.z * inv); o.w = f2bf(s.w * inv);
  *(ushort4*)(Abf + (size_t)(NQ + c) * K_IN + d0) = o;
}

// ---------- K3: query fp32 -> bf16 rows [0, 2048) of A ----------
__global__ void k_convert_q(const float* __restrict__ q, unsigned short* __restrict__ Abf) {
  size_t i4 = (size_t)blockIdx.x * blockDim.x + threadIdx.x;
  float4 v = *((const float4*)q + i4);
  ushort4 o; o.x = f2bf(v.x); o.y = f2bf(v.y); o.z = f2bf(v.z); o.w = f2bf(v.w);
  *((ushort4*)Abf + i4) = o;
}

// ---------- K4: W [K,E] fp32 -> Wt [E,K] bf16 (LDS-tiled transpose) ----------
__global__ void k_transpose_w(const float* __restrict__ W, unsigned short* __restrict__ Wt) {
  __shared__ float tile[64][65];
  int t = threadIdx.x;
  int k0 = blockIdx.x * 64, n0 = blockIdx.y * 64;
  int nl = t & 63, kb = (t >> 6) * 16;
  for (int r = 0; r < 16; ++r)
    tile[kb + r][nl] = W[(size_t)(k0 + kb + r) * EMB + n0 + nl];
  __syncthreads();
  int k2 = (t & 31) * 2, nb = (t >> 5) * 8;
  for (int r = 0; r < 8; ++r) {
    int n = nb + r;
    uint32_t lo = f2bf(tile[k2][n]);
    uint32_t hi = f2bf(tile[k2 + 1][n]);
    *(uint32_t*)(Wt + (size_t)(n0 + n) * K_IN + k0 + k2) = lo | (hi << 16);
  }
}

// ---------- K5: zero Z ----------
__global__ void k_zero(float* __restrict__ Z, int n4) {
  int i = blockIdx.x * blockDim.x + threadIdx.x;
  if (i < n4) ((float4*)Z)[i] = make_float4(0.f, 0.f, 0.f, 0.f);
}

// ---------- K6: bf16 MFMA GEMM, 128x128 tile, BK=64 (XOR-swizzled LDS), split-K=6 ----------
__global__ __launch_bounds__(256, 4) void k_gemm(
    const unsigned short* __restrict__ Abf, const unsigned short* __restrict__ Wt,
    const float* __restrict__ bias, float* __restrict__ Z) {
  __shared__ unsigned short As[128 * 64];
  __shared__ unsigned short Bs[128 * 64];
  int tid = threadIdx.x;
  int rowBase = blockIdx.y * 128;
  int colBase = blockIdx.x * 128;
  int kbase   = blockIdx.z * (K_IN / 6);   // 8192 per chunk

  // staging: thread -> tile row (tid>>3) (+32*i), LDS slot (tid&7); global granule XOR'd by row
  int rs   = tid >> 3;                 // 0..31
  int slot = tid & 7;
  int gg   = slot ^ (rs & 7);          // which global 16B granule this lane fetches
  const unsigned short* gA = Abf + (size_t)(rowBase + rs) * K_IN + kbase + gg * 8;
  const unsigned short* gB = Wt  + (size_t)(colBase + rs) * K_IN + kbase + gg * 8;
  unsigned short* lA = &As[tid * 8];   // byte offset tid*16 (wave-contiguous)
  unsigned short* lB = &Bs[tid * 8];
  const size_t rstep = (size_t)32 * K_IN;

  int lane = tid & 63, wid = tid >> 6;
  int wm = wid >> 1, wn = wid & 1;
  int lrow = lane & 15, q = lane >> 4;
  int key = lrow & 7;

  f32x4 acc[4][4] = {};

  for (int kt = 0; kt < 128; ++kt) {
    int ko = kt * 64;
    GLDS16(gA + ko,             lA);
    GLDS16(gA + ko + rstep,     lA + 2048);
    GLDS16(gA + ko + 2 * rstep, lA + 4096);
    GLDS16(gA + ko + 3 * rstep, lA + 6144);
    GLDS16(gB + ko,             lB);
    GLDS16(gB + ko + rstep,     lB + 2048);
    GLDS16(gB + ko + 2 * rstep, lB + 4096);
    GLDS16(gB + ko + 3 * rstep, lB + 6144);
    __syncthreads();
#pragma unroll
    for (int kk = 0; kk < 2; ++kk) {
      bf16x8 a[4], bb[4];
      int sl = (kk * 4 + q) ^ key;     // de-swizzle granule slot
#pragma unroll
      for (int i = 0; i < 4; ++i) {
        int rowA = wm * 64 + i * 16 + lrow;
        int rowB = wn * 64 + i * 16 + lrow;
        a[i]  = *(const bf16x8*)(&As[rowA * 64 + sl * 8]);
        bb[i] = *(const bf16x8*)(&Bs[rowB * 64 + sl * 8]);
      }
#pragma unroll
      for (int i = 0; i < 4; ++i)
#pragma unroll
        for (int j = 0; j < 4; ++j)
          acc[i][j] = __builtin_amdgcn_mfma_f32_16x16x32_bf16(a[i], bb[j], acc[i][j], 0, 0, 0);
    }
    __syncthreads();
  }

  int lquad = lane >> 4;
  bool addB = (blockIdx.z == 0);
#pragma unroll
  for (int i = 0; i < 4; ++i) {
#pragma unroll
    for (int j = 0; j < 4; ++j) {
      int m0 = rowBase + wm * 64 + i * 16 + lquad * 4;
      int n  = colBase + wn * 64 + j * 16 + lrow;
      float bv = addB ? bias[n] : 0.0f;
#pragma unroll
      for (int r = 0; r < 4; ++r)
        atomicAdd(&Z[(size_t)(m0 + r) * EMB + n], acc[i][j][r] + bv);
    }
  }
}

// ---------- K7: cosine scores (protos LDS-staged, norms fused) ----------
__global__ __launch_bounds__(256) void k_cosine(const float* __restrict__ Z,
                                                float* __restrict__ out) {
  __shared__ float Ps[64][132];   // padded: bank-minimal strided reads
  __shared__ float Qs[8][132];
  int t = threadIdx.x;
  int q0 = blockIdx.x * 8;
  int qi = t >> 5;     // 0..7 : query within block
  int c  = t & 31;     // classes c and c+32

  float dot0 = 0.f, dot1 = 0.f, qn = 0.f, pn0 = 0.f, pn1 = 0.f;

  for (int kc = 0; kc < EMB; kc += 128) {
    __syncthreads();
    // stage protos: 64 rows x 128 floats, coalesced 512B per row
#pragma unroll
    for (int j = 0; j < 8; ++j) {
      int f = j * 256 + t;            // float4 index
      int row = f >> 5, col4 = f & 31;
      float4 v = *(const float4*)(Z + (size_t)(NQ + row) * EMB + kc + col4 * 4);
      *(float4*)&Ps[row][col4 * 4] = v;
    }
    // stage queries: 8 rows x 128 floats
    {
      int row = t >> 5, col4 = t & 31;
      float4 v = *(const float4*)(Z + (size_t)(q0 + row) * EMB + kc + col4 * 4);
      *(float4*)&Qs[row][col4 * 4] = v;
    }
    __syncthreads();
#pragma unroll 4
    for (int kk = 0; kk < 32; ++kk) {
      float4 qv = *(const float4*)&Qs[qi][kk * 4];
      float4 p0 = *(const float4*)&Ps[c][kk * 4];
      float4 p1 = *(const float4*)&Ps[c + 32][kk * 4];
      dot0 += qv.x * p0.x + qv.y * p0.y + qv.z * p0.z + qv.w * p0.w;
      dot1 += qv.x * p1.x + qv.y * p1.y + qv.z * p1.z + qv.w * p1.w;
      qn   += qv.x * qv.x + qv.y * qv.y + qv.z * qv.z + qv.w * qv.w;
      pn0  += p0.x * p0.x + p0.y * p0.y + p0.z * p0.z + p0.w * p0.w;
      pn1  += p1.x * p1.x + p1.y * p1.y + p1.z * p1.z + p1.w * p1.w;
    }
  }
  float nq = sqrtf(qn);
  out[(size_t)(q0 + qi) * NW + c]      = dot0 / fmaxf(nq * sqrtf(pn0), EPS);
  out[(size_t)(q0 + qi) * NW + c + 32] = dot1 / fmaxf(nq * sqrtf(pn1), EPS);
}

extern "C" void kernel_launch(void* const* d_in, const int* in_sizes, int n_in,
                              void* d_out, int out_size, void* d_ws, size_t ws_size,
                              hipStream_t stream) {
  const float* sup    = (const float*)d_in[0];
  const int*   labels = (const int*)d_in[1];
  const float* qry    = (const float*)d_in[2];
  const float* W      = (const float*)d_in[3];
  const float* bias   = (const float*)d_in[4];
  float* out = (float*)d_out;

  char* w = (char*)d_ws;
  unsigned short* Abf = (unsigned short*)w;                       // 213,909,504 B
  unsigned short* Wt  = (unsigned short*)(w + 213909504u);        // 201,326,592 B
  float* Z     = (float*)(w + 415236096u);                        //  17,825,792 B
  int* rowsIdx = (int*)(w + 433070336u);                          //       4,096 B
  int* counts  = (int*)(w + 433074432u);                          //         256 B

  k_build_index<<<1, 1024, 0, stream>>>(labels, rowsIdx, counts);
  k_proto_mean<<<dim3(48, 64), 256, 0, stream>>>(sup, rowsIdx, counts, Abf);
  k_convert_q<<<98304, 256, 0, stream>>>(qry, Abf);
  k_transpose_w<<<dim3(768, 32), 256, 0, stream>>>(W, Wt);
  k_zero<<<(MA * EMB / 4 + 255) / 256, 256, 0, stream>>>(Z, MA * EMB / 4);
  k_gemm<<<dim3(16, 17, 6), 256, 0, stream>>>(Abf, Wt, bias, Z);
  k_cosine<<<256, 256, 0, stream>>>(Z, out);
}